// Round 1
// baseline (58.251 us; speedup 1.0000x reference)
//
#include <hip/hip_runtime.h>

// GrCNetConvOnly: out[b] = sum_{c,d} relu(w[c,0]*h[b,d] + w[c,1]*r[b,d] + w[c,2]*t[b,d] + cb[c]) * fcw[c*D+d] + fcb
// B=16384, D=400, C=50. VALU-bound (~1.6e9 f32 ops -> ~21us floor).
// One wave handles 4 batch elements (amortizes fc_w reads 4x); lane covers d = lane + 64*i.

constexpr int D = 400;
constexpr int C = 50;

__global__ __launch_bounds__(256, 4) void grcnet_fused(
    const float* __restrict__ entity_emb,
    const float* __restrict__ relation_emb,
    const float* __restrict__ conv_w,     // (C,1,1,3) flat: c*3+k
    const float* __restrict__ conv_b,     // (C)
    const float* __restrict__ fc_w,       // (1, C*D) flat: c*D+d
    const float* __restrict__ fc_b,       // (1)
    const int*   __restrict__ batch_inputs, // (B,3)
    float* __restrict__ out,              // (B)
    int nB)
{
    const int lane = threadIdx.x & 63;
    const int wave = threadIdx.x >> 6;
    const int b0   = (blockIdx.x * 4 + wave) * 4;   // 4 consecutive b per wave
    if (b0 >= nB) return;

    // b0 is uniform within the wave; force SGPR so index loads become s_load.
    const int b0u = __builtin_amdgcn_readfirstlane(b0);
    const int* bi = batch_inputs + 3 * b0u;
    const int h0i = bi[0], r0i = bi[1], t0i = bi[2];
    const int h1i = bi[3], r1i = bi[4], t1i = bi[5];
    const int h2i = bi[6], r2i = bi[7], t2i = bi[8];
    const int h3i = bi[9], r3i = bi[10], t3i = bi[11];

    const float* eh0 = entity_emb  + (size_t)h0i * D;
    const float* er0 = relation_emb + (size_t)r0i * D;
    const float* et0 = entity_emb  + (size_t)t0i * D;
    const float* eh1 = entity_emb  + (size_t)h1i * D;
    const float* er1 = relation_emb + (size_t)r1i * D;
    const float* et1 = entity_emb  + (size_t)t1i * D;
    const float* eh2 = entity_emb  + (size_t)h2i * D;
    const float* er2 = relation_emb + (size_t)r2i * D;
    const float* et2 = entity_emb  + (size_t)t2i * D;
    const float* eh3 = entity_emb  + (size_t)h3i * D;
    const float* er3 = relation_emb + (size_t)r3i * D;
    const float* et3 = entity_emb  + (size_t)t3i * D;

    float acc0 = 0.f, acc1 = 0.f, acc2 = 0.f, acc3 = 0.f;

    for (int i = 0; i < 7; ++i) {
        const int d = lane + 64 * i;
        const bool act = (d < D);
        const int dc = act ? d : 0;   // clamped: loads stay in-bounds

        const float h0 = eh0[dc], r0 = er0[dc], t0 = et0[dc];
        const float h1 = eh1[dc], r1 = er1[dc], t1 = et1[dc];
        const float h2 = eh2[dc], r2 = er2[dc], t2 = et2[dc];
        const float h3 = eh3[dc], r3 = er3[dc], t3 = et3[dc];

        float la0 = 0.f, la1 = 0.f, la2 = 0.f, la3 = 0.f;
        const float* fp = fc_w + dc;

        #pragma unroll 10
        for (int c = 0; c < C; ++c) {
            // uniform addresses (loop counter + kernel arg) -> scalar loads
            const float wa = conv_w[3*c + 0];
            const float wb = conv_w[3*c + 1];
            const float wc = conv_w[3*c + 2];
            const float cb = conv_b[c];
            const float f  = fp[c * D];

            float s0 = fmaf(wa, h0, fmaf(wb, r0, fmaf(wc, t0, cb)));
            float s1 = fmaf(wa, h1, fmaf(wb, r1, fmaf(wc, t1, cb)));
            float s2 = fmaf(wa, h2, fmaf(wb, r2, fmaf(wc, t2, cb)));
            float s3 = fmaf(wa, h3, fmaf(wb, r3, fmaf(wc, t3, cb)));
            la0 = fmaf(fmaxf(s0, 0.f), f, la0);
            la1 = fmaf(fmaxf(s1, 0.f), f, la1);
            la2 = fmaf(fmaxf(s2, 0.f), f, la2);
            la3 = fmaf(fmaxf(s3, 0.f), f, la3);
        }
        if (act) { acc0 += la0; acc1 += la1; acc2 += la2; acc3 += la3; }
    }

    // wave-wide sum (64 lanes)
    #pragma unroll
    for (int off = 32; off > 0; off >>= 1) {
        acc0 += __shfl_xor(acc0, off);
        acc1 += __shfl_xor(acc1, off);
        acc2 += __shfl_xor(acc2, off);
        acc3 += __shfl_xor(acc3, off);
    }

    if (lane == 0) {
        const float fb = fc_b[0];
        out[b0 + 0] = acc0 + fb;
        out[b0 + 1] = acc1 + fb;
        out[b0 + 2] = acc2 + fb;
        out[b0 + 3] = acc3 + fb;
    }
}

extern "C" void kernel_launch(void* const* d_in, const int* in_sizes, int n_in,
                              void* d_out, int out_size, void* d_ws, size_t ws_size,
                              hipStream_t stream) {
    const float* entity_emb   = (const float*)d_in[0];
    const float* relation_emb = (const float*)d_in[1];
    const float* conv_w       = (const float*)d_in[2];
    const float* conv_b       = (const float*)d_in[3];
    const float* fc_w         = (const float*)d_in[4];
    const float* fc_b         = (const float*)d_in[5];
    const int*   batch_inputs = (const int*)d_in[6];
    float* out = (float*)d_out;

    const int nB = in_sizes[6] / 3;           // 16384
    const int blocks = (nB + 15) / 16;        // 16 b per block (4 waves x 4 b)
    grcnet_fused<<<blocks, 256, 0, stream>>>(
        entity_emb, relation_emb, conv_w, conv_b, fc_w, fc_b, batch_inputs, out, nB);
}